// Round 8
// baseline (83.095 us; speedup 1.0000x reference)
//
#include <hip/hip_runtime.h>
#include <math.h>

#define T_LR 20
#define T_HR 30
#define CCH  4
#define H0   256
#define W0   256
#define HH   512
#define WW   512
#define ABOVE 10000

typedef float f32x4 __attribute__((ext_vector_type(4)));

// ws layout (32-bit slots):
#define WS_FIDX  0    // 20 ints
#define WS_SIDX  32   // 20 ints
#define WS_ALPHA 64   // 20 floats
#define WS_BETA  96   // 20 floats
#define WS_VALID 128  // 20 ints
#define WS_CNT   160  // 480 ints (partial sums, 16 per frame)

// ---------------- Phase A1: per-HR-frame mask count (480 partial slots) ----------------
__global__ void rate_kernel(const int* __restrict__ hr_mask,
                            int* __restrict__ wsi) {
    int j = blockIdx.x >> 4;          // frame
    int slice = blockIdx.x & 15;      // 1/16 of frame
    const int elems = HH * WW / 16;   // 16384 ints per slice
    const uint4* p = (const uint4*)(hr_mask + (size_t)j * HH * WW + (size_t)slice * elems);
    int sum = 0;
    for (int e = threadIdx.x; e < elems / 4; e += blockDim.x) {
        uint4 v = p[e];
        sum += (int)(v.x + v.y + v.z + v.w);
    }
    for (int o = 32; o; o >>= 1) sum += __shfl_down(sum, o);
    __shared__ int ssum[4];
    if ((threadIdx.x & 63) == 0) ssum[threadIdx.x >> 6] = sum;
    __syncthreads();
    if (threadIdx.x == 0)
        wsi[WS_CNT + blockIdx.x] = ssum[0] + ssum[1] + ssum[2] + ssum[3];
}

// ---------------- Phase A2: first/second frame selection ----------------
__global__ void select_kernel(const int* __restrict__ lr_doy,
                              const int* __restrict__ hr_doy,
                              float* __restrict__ ws) {
    int i = threadIdx.x;
    if (i >= T_LR) return;
    const int* wsi_c = (const int*)ws;
    int doy = lr_doy[i];

    int fmin = ABOVE, fidx = 0;
    for (int j = 0; j < T_HR; j++) {
        int d = doy - hr_doy[j];
        if (d < 0) d = ABOVE;
        int cnt = 0;
        for (int k = 0; k < 16; k++) cnt += wsi_c[WS_CNT + 16 * j + k];
        float rate = (float)cnt / (float)(HH * WW);
        if (rate > 0.5f) d = ABOVE;
        if (d < fmin) { fmin = d; fidx = j; }   // first-occurrence argmin
    }
    int smin = ABOVE, sidx = 0;
    for (int j = 0; j < T_HR; j++) {
        int d = doy - hr_doy[j];
        if (d < 0) d = ABOVE;
        int cnt = 0;
        for (int k = 0; k < 16; k++) cnt += wsi_c[WS_CNT + 16 * j + k];
        float rate = (float)cnt / (float)(HH * WW);
        if (rate > 0.5f) d = ABOVE;
        if (j == fidx) d = ABOVE;
        if (d < smin) { smin = d; sidx = j; }
    }
    int valid = (fmin < ABOVE) && (smin < ABOVE);
    float fv = (float)hr_doy[fidx], sv = (float)hr_doy[sidx];
    float denom = sv - fv;

    int* wsi = (int*)ws;
    wsi[WS_FIDX + i] = fidx;
    wsi[WS_SIDX + i] = sidx;
    ws[WS_ALPHA + i] = (sv - (float)doy) / denom;   // weight on g1
    ws[WS_BETA + i]  = ((float)doy - fv) / denom;   // weight on g2
    wsi[WS_VALID + i] = valid;
}

// ---------------- Phase B: fused main kernel (separable PSF) ----------------
// grid (16,16,80). XCD-chunk swizzle. 3x3 Gaussian = [ga,gb,ga] x [ga,gb,ga].
// Thread (ty,tx4) stages the horizontal blur H of ITS OWN output row for both
// images; the center quad stays in registers (no re-read). Edge rows 0/33 are
// staged by threads 0..31. All LDS traffic is aligned b128.
__launch_bounds__(256)
__global__ void fuse_kernel(const float* __restrict__ lr_data,
                            const float* __restrict__ hr_data,
                            const int* __restrict__ lr_mask,
                            const int* __restrict__ hr_mask,
                            const float* __restrict__ ws,
                            float* __restrict__ out,
                            float ga, float gb) {
    // bijective XCD chunk swizzle (20480 blocks, 8 XCDs, lin%8 == XCD)
    const int lin = blockIdx.x + (blockIdx.y << 4) + (blockIdx.z << 8);
    const int q = lin >> 3;
    const int z = (lin & 7) * 10 + (q >> 8);   // z in [0,80)
    const int t = q & 255;                     // tile in [0,256)
    const int i  = z >> 2;
    const int ch = z & 3;
    const int x0 = (t & 15) * 32;
    const int y0 = (t >> 4) * 32;
    const int tid = threadIdx.x;
    const int ty = tid >> 3, tx4 = tid & 7;
    const int y = y0 + ty, x = x0 + tx4 * 4;

    const int* wsi = (const int*)ws;
    const int f       = wsi[WS_FIDX + i];
    const int s       = wsi[WS_SIDX + i];
    const float alpha = ws[WS_ALPHA + i];
    const float beta  = ws[WS_BETA + i];
    const int valid   = wsi[WS_VALID + i];

    __shared__ float Hs[2][34][36];   // horizontal-blurred HR rows (y0-1 .. y0+32)
    __shared__ float hxs[18][36];     // horizontally-interpolated LR at HR res

    const float* g0 = hr_data + ((size_t)f * CCH + ch) * HH * WW;
    const float* g1 = hr_data + ((size_t)s * CCH + ch) * HH * WW;

    // ---- main staging: own row (rr=ty+1, quad tx4) for both imgs; keep centers ----
    f32x4 xc0, xc1;
    {
        const float* gp = g0 + (size_t)y * WW;
        f32x4 v = *(const f32x4*)(gp + x);
        xc0 = v;
        float xl = (x > 0)      ? gp[x - 1] : 0.f;
        float xr = (x + 4 < WW) ? gp[x + 4] : 0.f;
        f32x4 H;
        H.x = ga * (xl  + v.y) + gb * v.x;
        H.y = ga * (v.x + v.z) + gb * v.y;
        H.z = ga * (v.y + v.w) + gb * v.z;
        H.w = ga * (v.z + xr ) + gb * v.w;
        *(f32x4*)&Hs[0][ty + 1][tx4 * 4] = H;
    }
    {
        const float* gp = g1 + (size_t)y * WW;
        f32x4 v = *(const f32x4*)(gp + x);
        xc1 = v;
        float xl = (x > 0)      ? gp[x - 1] : 0.f;
        float xr = (x + 4 < WW) ? gp[x + 4] : 0.f;
        f32x4 H;
        H.x = ga * (xl  + v.y) + gb * v.x;
        H.y = ga * (v.x + v.z) + gb * v.y;
        H.z = ga * (v.y + v.w) + gb * v.z;
        H.w = ga * (v.z + xr ) + gb * v.w;
        *(f32x4*)&Hs[1][ty + 1][tx4 * 4] = H;
    }

    // ---- edge rows 0 and 33: 2 imgs x 2 rows x 8 quads = 32 tasks ----
    if (tid < 32) {
        int img  = tid >> 4;         // 0..1
        int top  = (tid >> 3) & 1;   // 0 -> rr 0, 1 -> rr 33
        int quad = tid & 7;
        int rr = top ? 33 : 0;
        int gy = y0 - 1 + rr;        // y0-1 or y0+32
        f32x4 H = {0.f, 0.f, 0.f, 0.f};
        if (gy >= 0 && gy < HH) {    // zero-pad rows
            const float* gp = (img ? g1 : g0) + (size_t)gy * WW;
            int gx = x0 + quad * 4;
            f32x4 v = *(const f32x4*)(gp + gx);
            float xl = (gx > 0)      ? gp[gx - 1] : 0.f;
            float xr = (gx + 4 < WW) ? gp[gx + 4] : 0.f;
            H.x = ga * (xl  + v.y) + gb * v.x;
            H.y = ga * (v.x + v.z) + gb * v.y;
            H.z = ga * (v.y + v.w) + gb * v.z;
            H.w = ga * (v.z + xr ) + gb * v.w;
        }
        *(f32x4*)&Hs[img][rr][quad * 4] = H;
    }

    // ---- stage hx: 18 rows x 8 quads (clamp-to-edge bilinear, horizontal) ----
    const int ly0 = (y0 >> 1) - 1;
    if (tid < 144) {
        int r = tid >> 3, tq = tid & 7;
        int gy = min(max(ly0 + r, 0), H0 - 1);
        const float* lp = lr_data + ((size_t)i * CCH + ch) * H0 * W0 + (size_t)gy * W0;
        int J = (x0 >> 1) + tq * 2;
        float vm = lp[max(J - 1, 0)];
        float v0 = lp[J];
        float v1 = lp[J + 1];
        float v2 = lp[min(J + 2, W0 - 1)];
        f32x4 hx;
        hx.x = 0.75f * v0 + 0.25f * vm;
        hx.y = 0.75f * v0 + 0.25f * v1;
        hx.z = 0.75f * v1 + 0.25f * v0;
        hx.w = 0.75f * v1 + 0.25f * v2;
        *(f32x4*)&hxs[r][tq * 4] = hx;
    }

    // ---- mask loads (ch==0 only), issued pre-barrier ----
    const int jy = y >> 1;
    int4 mf = make_int4(0, 0, 0, 0), ms = make_int4(0, 0, 0, 0);
    int m0 = 0, m1 = 0;
    if (ch == 0) {
        mf = *(const int4*)(hr_mask + ((size_t)f * HH + y) * WW + x);
        ms = *(const int4*)(hr_mask + ((size_t)s * HH + y) * WW + x);
        const int* lm = lr_mask + ((size_t)i * H0 + jy) * W0;
        m0 = lm[x >> 1];
        m1 = lm[(x >> 1) + 1];
    }
    __syncthreads();

    // ---- vertical PSF pass (centers already in regs) ----
    const int c = tx4 * 4;
    f32x4 hu0 = *(const f32x4*)&Hs[0][ty    ][c];
    f32x4 hm0 = *(const f32x4*)&Hs[0][ty + 1][c];
    f32x4 hd0 = *(const f32x4*)&Hs[0][ty + 2][c];
    f32x4 hu1 = *(const f32x4*)&Hs[1][ty    ][c];
    f32x4 hm1 = *(const f32x4*)&Hs[1][ty + 1][c];
    f32x4 hd1 = *(const f32x4*)&Hs[1][ty + 2][c];
    f32x4 hp0 = xc0 - (ga * (hu0 + hd0) + gb * hm0);
    f32x4 hp1 = xc1 - (ga * (hu1 + hd1) + gb * hm1);

    // ---- vertical bilinear ----
    const int rc = jy - ly0;
    const int rn = jy + ((y & 1) ? 1 : -1) - ly0;
    f32x4 ha = *(const f32x4*)&hxs[rc][c];
    f32x4 hb = *(const f32x4*)&hxs[rn][c];
    f32x4 lu = 0.75f * ha + 0.25f * hb;

    // ---- stores (nontemporal streaming) ----
    const size_t outM  = (size_t)T_LR * CCH * HH * WW;
    const size_t outLU = outM + (size_t)T_LR * HH * WW;
    const size_t oidx = (((size_t)i * CCH + ch) * HH + y) * WW + x;

    f32x4 fh = lu + alpha * hp0 + beta * hp1;
    __builtin_nontemporal_store(fh, (f32x4*)&out[oidx]);
    __builtin_nontemporal_store(lu, (f32x4*)&out[outLU + oidx]);

    // ---- final_mask: only channel-0 blocks ----
    if (ch == 0) {
        int nv = !valid;
        f32x4 mo;
        mo.x = (m0 | mf.x | ms.x | nv) ? 1.f : 0.f;
        mo.y = (m0 | mf.y | ms.y | nv) ? 1.f : 0.f;
        mo.z = (m1 | mf.z | ms.z | nv) ? 1.f : 0.f;
        mo.w = (m1 | mf.w | ms.w | nv) ? 1.f : 0.f;
        __builtin_nontemporal_store(mo, (f32x4*)&out[outM + ((size_t)i * HH + y) * WW + x]);
    }
}

extern "C" void kernel_launch(void* const* d_in, const int* in_sizes, int n_in,
                              void* d_out, int out_size, void* d_ws, size_t ws_size,
                              hipStream_t stream) {
    const float* lr_data = (const float*)d_in[0];
    const float* hr_data = (const float*)d_in[1];
    const int* lr_doy    = (const int*)d_in[2];
    const int* hr_doy    = (const int*)d_in[3];
    const int* lr_mask   = (const int*)d_in[4];
    const int* hr_mask   = (const int*)d_in[5];
    float* out = (float*)d_out;
    float* ws  = (float*)d_ws;
    int* wsi   = (int*)d_ws;

    // Separable PSF: k = [ga,gb,ga] (x) [ga,gb,ga], per-axis normalized.
    // e2 == e1^2 exactly, so (1+2e1)^2 == 1+4e1+4e2 == full kernel sum.
    double sigma = sqrt(-2.0 * log(0.4)) / M_PI;
    double e1 = exp(-1.0 / (2.0 * sigma * sigma));
    double axis_sum = 1.0 + 2.0 * e1;
    float ga = (float)(e1 / axis_sum);
    float gb = (float)(1.0 / axis_sum);

    rate_kernel<<<T_HR * 16, 256, 0, stream>>>(hr_mask, wsi);
    select_kernel<<<1, 64, 0, stream>>>(lr_doy, hr_doy, ws);

    dim3 grid(WW / 32, HH / 32, T_LR * CCH);
    fuse_kernel<<<grid, 256, 0, stream>>>(lr_data, hr_data, lr_mask, hr_mask,
                                          ws, out, ga, gb);
}

// Round 9
// 74.631 us; speedup vs baseline: 1.1134x; 1.1134x over previous
//
#include <hip/hip_runtime.h>
#include <math.h>

#define T_LR 20
#define T_HR 30
#define CCH  4
#define H0   256
#define W0   256
#define HH   512
#define WW   512
#define ABOVE 10000

typedef float f32x4 __attribute__((ext_vector_type(4)));

// ws layout (32-bit slots):
#define WS_FIDX  0    // 20 ints
#define WS_SIDX  32   // 20 ints
#define WS_ALPHA 64   // 20 floats
#define WS_BETA  96   // 20 floats
#define WS_VALID 128  // 20 ints
#define WS_CNT   160  // 480 ints (partial sums, 16 per frame)

// ---------------- Phase A1: per-HR-frame mask count (480 partial slots) ----------------
__global__ void rate_kernel(const int* __restrict__ hr_mask,
                            int* __restrict__ wsi) {
    int j = blockIdx.x >> 4;          // frame
    int slice = blockIdx.x & 15;      // 1/16 of frame
    const int elems = HH * WW / 16;   // 16384 ints per slice
    const uint4* p = (const uint4*)(hr_mask + (size_t)j * HH * WW + (size_t)slice * elems);
    int sum = 0;
    for (int e = threadIdx.x; e < elems / 4; e += blockDim.x) {
        uint4 v = p[e];
        sum += (int)(v.x + v.y + v.z + v.w);
    }
    for (int o = 32; o; o >>= 1) sum += __shfl_down(sum, o);
    __shared__ int ssum[4];
    if ((threadIdx.x & 63) == 0) ssum[threadIdx.x >> 6] = sum;
    __syncthreads();
    if (threadIdx.x == 0)
        wsi[WS_CNT + blockIdx.x] = ssum[0] + ssum[1] + ssum[2] + ssum[3];
}

// ---------------- Phase A2: first/second frame selection ----------------
// Cooperative: threads 0..29 reduce their frame's 16 partials into LDS once;
// selection threads then read rates from LDS (no redundant 960-load loops).
__global__ void select_kernel(const int* __restrict__ lr_doy,
                              const int* __restrict__ hr_doy,
                              float* __restrict__ ws) {
    __shared__ int masked[T_HR];   // rate > 0.5 flag per frame
    __shared__ int hdoy[T_HR];
    const int* wsi_c = (const int*)ws;
    int tid = threadIdx.x;
    if (tid < T_HR) {
        int cnt = 0;
        #pragma unroll
        for (int k = 0; k < 16; k++) cnt += wsi_c[WS_CNT + 16 * tid + k];
        masked[tid] = (float)cnt / (float)(HH * WW) > 0.5f;
        hdoy[tid] = hr_doy[tid];
    }
    __syncthreads();
    int i = tid;
    if (i >= T_LR) return;
    int doy = lr_doy[i];

    int fmin = ABOVE, fidx = 0;
    #pragma unroll
    for (int j = 0; j < T_HR; j++) {
        int d = doy - hdoy[j];
        if (d < 0) d = ABOVE;
        if (masked[j]) d = ABOVE;
        if (d < fmin) { fmin = d; fidx = j; }   // first-occurrence argmin
    }
    int smin = ABOVE, sidx = 0;
    #pragma unroll
    for (int j = 0; j < T_HR; j++) {
        int d = doy - hdoy[j];
        if (d < 0) d = ABOVE;
        if (masked[j]) d = ABOVE;
        if (j == fidx) d = ABOVE;
        if (d < smin) { smin = d; sidx = j; }
    }
    int valid = (fmin < ABOVE) && (smin < ABOVE);
    float fv = (float)hdoy[fidx], sv = (float)hdoy[sidx];
    float denom = sv - fv;

    int* wsi = (int*)ws;
    wsi[WS_FIDX + i] = fidx;
    wsi[WS_SIDX + i] = sidx;
    ws[WS_ALPHA + i] = (sv - (float)doy) / denom;   // weight on g1
    ws[WS_BETA + i]  = ((float)doy - fv) / denom;   // weight on g2
    wsi[WS_VALID + i] = valid;
}

// ---------------- Phase B: fused main kernel (separable PSF) ----------------
// grid (16,16,80). XCD-chunk swizzle. 3x3 Gaussian = [ga,gb,ga] x [ga,gb,ga].
// Thread (ty,tx4) stages the horizontal blur H of ITS OWN output row for both
// images; the center quad stays in registers (no re-read). Edge rows 0/33 are
// staged by threads 0..31. All LDS traffic is aligned b128.
__launch_bounds__(256)
__global__ void fuse_kernel(const float* __restrict__ lr_data,
                            const float* __restrict__ hr_data,
                            const int* __restrict__ lr_mask,
                            const int* __restrict__ hr_mask,
                            const float* __restrict__ ws,
                            float* __restrict__ out,
                            float ga, float gb) {
    // bijective XCD chunk swizzle (20480 blocks, 8 XCDs, lin%8 == XCD)
    const int lin = blockIdx.x + (blockIdx.y << 4) + (blockIdx.z << 8);
    const int q = lin >> 3;
    const int z = (lin & 7) * 10 + (q >> 8);   // z in [0,80)
    const int t = q & 255;                     // tile in [0,256)
    const int i  = z >> 2;
    const int ch = z & 3;
    const int x0 = (t & 15) * 32;
    const int y0 = (t >> 4) * 32;
    const int tid = threadIdx.x;
    const int ty = tid >> 3, tx4 = tid & 7;
    const int y = y0 + ty, x = x0 + tx4 * 4;

    const int* wsi = (const int*)ws;
    const int f       = wsi[WS_FIDX + i];
    const int s       = wsi[WS_SIDX + i];
    const float alpha = ws[WS_ALPHA + i];
    const float beta  = ws[WS_BETA + i];
    const int valid   = wsi[WS_VALID + i];

    __shared__ float Hs[2][34][36];   // horizontal-blurred HR rows (y0-1 .. y0+32)
    __shared__ float hxs[18][36];     // horizontally-interpolated LR at HR res

    const float* g0 = hr_data + ((size_t)f * CCH + ch) * HH * WW;
    const float* g1 = hr_data + ((size_t)s * CCH + ch) * HH * WW;

    // ---- main staging: own row (rr=ty+1, quad tx4) for both imgs; keep centers ----
    f32x4 xc0, xc1;
    {
        const float* gp = g0 + (size_t)y * WW;
        f32x4 v = *(const f32x4*)(gp + x);
        xc0 = v;
        float xl = (x > 0)      ? gp[x - 1] : 0.f;
        float xr = (x + 4 < WW) ? gp[x + 4] : 0.f;
        f32x4 H;
        H.x = ga * (xl  + v.y) + gb * v.x;
        H.y = ga * (v.x + v.z) + gb * v.y;
        H.z = ga * (v.y + v.w) + gb * v.z;
        H.w = ga * (v.z + xr ) + gb * v.w;
        *(f32x4*)&Hs[0][ty + 1][tx4 * 4] = H;
    }
    {
        const float* gp = g1 + (size_t)y * WW;
        f32x4 v = *(const f32x4*)(gp + x);
        xc1 = v;
        float xl = (x > 0)      ? gp[x - 1] : 0.f;
        float xr = (x + 4 < WW) ? gp[x + 4] : 0.f;
        f32x4 H;
        H.x = ga * (xl  + v.y) + gb * v.x;
        H.y = ga * (v.x + v.z) + gb * v.y;
        H.z = ga * (v.y + v.w) + gb * v.z;
        H.w = ga * (v.z + xr ) + gb * v.w;
        *(f32x4*)&Hs[1][ty + 1][tx4 * 4] = H;
    }

    // ---- edge rows 0 and 33: 2 imgs x 2 rows x 8 quads = 32 tasks ----
    if (tid < 32) {
        int img  = tid >> 4;         // 0..1
        int top  = (tid >> 3) & 1;   // 0 -> rr 0, 1 -> rr 33
        int quad = tid & 7;
        int rr = top ? 33 : 0;
        int gy = y0 - 1 + rr;        // y0-1 or y0+32
        f32x4 H = {0.f, 0.f, 0.f, 0.f};
        if (gy >= 0 && gy < HH) {    // zero-pad rows
            const float* gp = (img ? g1 : g0) + (size_t)gy * WW;
            int gx = x0 + quad * 4;
            f32x4 v = *(const f32x4*)(gp + gx);
            float xl = (gx > 0)      ? gp[gx - 1] : 0.f;
            float xr = (gx + 4 < WW) ? gp[gx + 4] : 0.f;
            H.x = ga * (xl  + v.y) + gb * v.x;
            H.y = ga * (v.x + v.z) + gb * v.y;
            H.z = ga * (v.y + v.w) + gb * v.z;
            H.w = ga * (v.z + xr ) + gb * v.w;
        }
        *(f32x4*)&Hs[img][rr][quad * 4] = H;
    }

    // ---- stage hx: 18 rows x 8 quads (clamp-to-edge bilinear, horizontal) ----
    const int ly0 = (y0 >> 1) - 1;
    if (tid < 144) {
        int r = tid >> 3, tq = tid & 7;
        int gy = min(max(ly0 + r, 0), H0 - 1);
        const float* lp = lr_data + ((size_t)i * CCH + ch) * H0 * W0 + (size_t)gy * W0;
        int J = (x0 >> 1) + tq * 2;
        float vm = lp[max(J - 1, 0)];
        float v0 = lp[J];
        float v1 = lp[J + 1];
        float v2 = lp[min(J + 2, W0 - 1)];
        f32x4 hx;
        hx.x = 0.75f * v0 + 0.25f * vm;
        hx.y = 0.75f * v0 + 0.25f * v1;
        hx.z = 0.75f * v1 + 0.25f * v0;
        hx.w = 0.75f * v1 + 0.25f * v2;
        *(f32x4*)&hxs[r][tq * 4] = hx;
    }

    // ---- mask loads (ch==0 only), issued pre-barrier ----
    const int jy = y >> 1;
    int4 mf = make_int4(0, 0, 0, 0), ms = make_int4(0, 0, 0, 0);
    int m0 = 0, m1 = 0;
    if (ch == 0) {
        mf = *(const int4*)(hr_mask + ((size_t)f * HH + y) * WW + x);
        ms = *(const int4*)(hr_mask + ((size_t)s * HH + y) * WW + x);
        const int* lm = lr_mask + ((size_t)i * H0 + jy) * W0;
        m0 = lm[x >> 1];
        m1 = lm[(x >> 1) + 1];
    }
    __syncthreads();

    // ---- vertical PSF pass (centers already in regs) ----
    const int c = tx4 * 4;
    f32x4 hu0 = *(const f32x4*)&Hs[0][ty    ][c];
    f32x4 hm0 = *(const f32x4*)&Hs[0][ty + 1][c];
    f32x4 hd0 = *(const f32x4*)&Hs[0][ty + 2][c];
    f32x4 hu1 = *(const f32x4*)&Hs[1][ty    ][c];
    f32x4 hm1 = *(const f32x4*)&Hs[1][ty + 1][c];
    f32x4 hd1 = *(const f32x4*)&Hs[1][ty + 2][c];
    f32x4 hp0 = xc0 - (ga * (hu0 + hd0) + gb * hm0);
    f32x4 hp1 = xc1 - (ga * (hu1 + hd1) + gb * hm1);

    // ---- vertical bilinear ----
    const int rc = jy - ly0;
    const int rn = jy + ((y & 1) ? 1 : -1) - ly0;
    f32x4 ha = *(const f32x4*)&hxs[rc][c];
    f32x4 hb = *(const f32x4*)&hxs[rn][c];
    f32x4 lu = 0.75f * ha + 0.25f * hb;

    // ---- stores (nontemporal streaming) ----
    const size_t outM  = (size_t)T_LR * CCH * HH * WW;
    const size_t outLU = outM + (size_t)T_LR * HH * WW;
    const size_t oidx = (((size_t)i * CCH + ch) * HH + y) * WW + x;

    f32x4 fh = lu + alpha * hp0 + beta * hp1;
    __builtin_nontemporal_store(fh, (f32x4*)&out[oidx]);
    __builtin_nontemporal_store(lu, (f32x4*)&out[outLU + oidx]);

    // ---- final_mask: only channel-0 blocks ----
    if (ch == 0) {
        int nv = !valid;
        f32x4 mo;
        mo.x = (m0 | mf.x | ms.x | nv) ? 1.f : 0.f;
        mo.y = (m0 | mf.y | ms.y | nv) ? 1.f : 0.f;
        mo.z = (m1 | mf.z | ms.z | nv) ? 1.f : 0.f;
        mo.w = (m1 | mf.w | ms.w | nv) ? 1.f : 0.f;
        __builtin_nontemporal_store(mo, (f32x4*)&out[outM + ((size_t)i * HH + y) * WW + x]);
    }
}

extern "C" void kernel_launch(void* const* d_in, const int* in_sizes, int n_in,
                              void* d_out, int out_size, void* d_ws, size_t ws_size,
                              hipStream_t stream) {
    const float* lr_data = (const float*)d_in[0];
    const float* hr_data = (const float*)d_in[1];
    const int* lr_doy    = (const int*)d_in[2];
    const int* hr_doy    = (const int*)d_in[3];
    const int* lr_mask   = (const int*)d_in[4];
    const int* hr_mask   = (const int*)d_in[5];
    float* out = (float*)d_out;
    float* ws  = (float*)d_ws;
    int* wsi   = (int*)d_ws;

    // Separable PSF: k = [ga,gb,ga] (x) [ga,gb,ga], per-axis normalized.
    // e2 == e1^2 exactly, so (1+2e1)^2 == 1+4e1+4e2 == full kernel sum.
    double sigma = sqrt(-2.0 * log(0.4)) / M_PI;
    double e1 = exp(-1.0 / (2.0 * sigma * sigma));
    double axis_sum = 1.0 + 2.0 * e1;
    float ga = (float)(e1 / axis_sum);
    float gb = (float)(1.0 / axis_sum);

    rate_kernel<<<T_HR * 16, 256, 0, stream>>>(hr_mask, wsi);
    select_kernel<<<1, 64, 0, stream>>>(lr_doy, hr_doy, ws);

    dim3 grid(WW / 32, HH / 32, T_LR * CCH);
    fuse_kernel<<<grid, 256, 0, stream>>>(lr_data, hr_data, lr_mask, hr_mask,
                                          ws, out, ga, gb);
}